// Round 26
// baseline (64.774 us; speedup 1.0000x reference)
//
#include <hip/hip_runtime.h>
#include <float.h>

#define BLK 256
#define NB 8
#define NPTS 8192
#define WPB 4      // waves per block
#define RPW 2      // 32-row strips (A fragments) per wave
#define CSPLIT 8   // column chunks per (batch, dir)
#define GPTS 64    // points per group (2 tiles)
#define NG (NPTS / CSPLIT / GPTS)   // 16 groups per chunk

typedef short bf16x8 __attribute__((ext_vector_type(8)));
typedef float f32x16 __attribute__((ext_vector_type(16)));

static __device__ __forceinline__ unsigned short f2bf(float f) {   // RNE f32->bf16
    union { float f; unsigned int u; } v; v.f = f;
    unsigned int u = v.u + 0x7FFFu + ((v.u >> 16) & 1u);
    return (unsigned short)(u >> 16);
}
static __device__ __forceinline__ float bf2f(unsigned short h) {
    union { unsigned int u; float f; } v; v.u = ((unsigned int)h) << 16;
    return v.f;
}

// Prep + fused output-init (saves the separate init_out launch).
// Emits BOTH layouts for BOTH point sets (K=16 bf16 slots; r13/r17-verified):
//   query layout:  [qh0..2, ql0..2, qh0..2, ql0..2, 1, 1, x2h, x2l]
//   target layout: [th0..2, th0..2, tl0..2, tl0..2, wh, wl, 1, 1], t=-2y, w=||y||^2
// Sum_k A_k*B_k = ||x||^2 + ||y||^2 - 2 x.y  (bf16 products exact in f32).
__global__ __launch_bounds__(BLK) void prep_kernel(
    const float* __restrict__ xyz1, const float* __restrict__ xyz2,
    unsigned short* __restrict__ Aq1, unsigned short* __restrict__ Bt1,
    unsigned short* __restrict__ Aq2, unsigned short* __restrict__ Bt2,
    int* __restrict__ outI, int npts)
{
    const int i = blockIdx.x * BLK + threadIdx.x;
    if (i >= npts) return;
    outI[i]        = 0x7F800000;   // +inf bits; atomicMin-as-int = float min (r10-r25 proven)
    outI[i + npts] = 0x7F800000;
    const unsigned short one = 0x3F80;
    const float* srcs[2] = { xyz1, xyz2 };
    unsigned short* aouts[2] = { Aq1, Aq2 };
    unsigned short* bouts[2] = { Bt1, Bt2 };
#pragma unroll
    for (int s = 0; s < 2; ++s) {
        const float p0 = srcs[s][3*(size_t)i], p1 = srcs[s][3*(size_t)i+1], p2 = srcs[s][3*(size_t)i+2];
        {
            const unsigned short h0 = f2bf(p0), h1 = f2bf(p1), h2 = f2bf(p2);
            const unsigned short l0 = f2bf(p0 - bf2f(h0)), l1 = f2bf(p1 - bf2f(h1)), l2 = f2bf(p2 - bf2f(h2));
            const float q2 = fmaf(p0, p0, fmaf(p1, p1, p2 * p2));
            const unsigned short q2h = f2bf(q2), q2l = f2bf(q2 - bf2f(q2h));
            unsigned short* o = aouts[s] + 16*(size_t)i;
            o[0]=h0; o[1]=h1; o[2]=h2; o[3]=l0; o[4]=l1; o[5]=l2;
            o[6]=h0; o[7]=h1; o[8]=h2; o[9]=l0; o[10]=l1; o[11]=l2;
            o[12]=one; o[13]=one; o[14]=q2h; o[15]=q2l;
        }
        {
            const float t0 = -2.f*p0, t1 = -2.f*p1, t2 = -2.f*p2;
            const unsigned short h0 = f2bf(t0), h1 = f2bf(t1), h2 = f2bf(t2);
            const unsigned short l0 = f2bf(t0 - bf2f(h0)), l1 = f2bf(t1 - bf2f(h1)), l2 = f2bf(t2 - bf2f(h2));
            const float w = fmaf(p0, p0, fmaf(p1, p1, p2 * p2));
            const unsigned short wh = f2bf(w), wl = f2bf(w - bf2f(wh));
            unsigned short* o = bouts[s] + 16*(size_t)i;
            o[0]=h0; o[1]=h1; o[2]=h2; o[3]=h0; o[4]=h1; o[5]=h2;
            o[6]=l0; o[7]=l1; o[8]=l2; o[9]=l0; o[10]=l1; o[11]=l2;
            o[12]=wh; o[13]=wl; o[14]=one; o[15]=one;
        }
    }
}

struct G2 { bf16x8 v0, v1; };

// Row-min MFMA passes — r25 balanced core, CSPLIT=8 for finer dispatch
// granularity (4096 blocks -> smaller tail at the 4-blocks/CU residency cap).
// Roles: blockIdx.x&15 -> 2 roles per XCD, per-XCD B working set 512 KB
// (L2-fit preserved; r23-proven FETCH win).
__global__ __launch_bounds__(BLK, 4) void chamfer_mfma(
    const bf16x8* __restrict__ Aq1, const bf16x8* __restrict__ Bt1,
    const bf16x8* __restrict__ Aq2, const bf16x8* __restrict__ Bt2,
    int* __restrict__ outI)
{
    const int wave  = threadIdx.x >> 6;
    const int lane  = threadIdx.x & 63;
    const int l31   = lane & 31;
    const int khalf = lane >> 5;

    const int zrole = blockIdx.x & 15;     // role; xcd = blockIdx.x % 8
    const int strip = blockIdx.x >> 4;     // [0, 32)
    const int dir   = zrole >> 3;
    const int chunk = zrole & 7;
    const int batch = blockIdx.y;

    const bf16x8* __restrict__ A  = dir ? Aq2 : Aq1;
    const bf16x8* __restrict__ Bt = dir ? Bt1 : Bt2;
    int* outbase = outI + (size_t)dir * NB * NPTS + (size_t)batch * NPTS;

    const size_t pbase = (size_t)batch * NPTS;
    const int r0 = (strip * WPB + wave) * (RPW * 32);

    bf16x8 afrag[RPW];
#pragma unroll
    for (int r = 0; r < RPW; ++r)
        afrag[r] = A[(pbase + r0 + r * 32 + l31) * 2 + khalf];

    float acc[RPW][16];
#pragma unroll
    for (int r = 0; r < RPW; ++r)
#pragma unroll
        for (int i = 0; i < 16; ++i) acc[r][i] = FLT_MAX;

    const size_t cbase = pbase + (size_t)chunk * (NPTS / CSPLIT);   // chunk point base

    auto LOADG = [&](int g) -> G2 {
        const size_t m = cbase + (size_t)g * GPTS + l31;
        G2 p;
        p.v0 = Bt[(m     ) * 2 + khalf];
        p.v1 = Bt[(m + 32) * 2 + khalf];
        return p;
    };

    const f32x16 zero = {};
    auto CONSUME = [&](const G2& p) {
#pragma unroll
        for (int r = 0; r < RPW; ++r) {    // 2 d-tiles live at a time
            const f32x16 dA = __builtin_amdgcn_mfma_f32_32x32x16_bf16(afrag[r], p.v0, zero, 0, 0, 0);
            const f32x16 dB = __builtin_amdgcn_mfma_f32_32x32x16_bf16(afrag[r], p.v1, zero, 0, 0, 0);
#pragma unroll
            for (int i = 0; i < 16; ++i)   // one fused v_min3 folds both tiles
                acc[r][i] = fminf(fminf(dA[i], dB[i]), acc[r][i]);
        }
    };

    // 1-group-ahead pipeline (static names — rule #20).
    G2 cur = LOADG(0);
    for (int g = 0; g < NG; ++g) {
        G2 nxt = (g + 1 < NG) ? LOADG(g + 1) : cur;
        CONSUME(cur);
        cur = nxt;
    }

    // Epilogue: butterfly min over the 32 lanes (cols) of each khalf group,
    // then lane l31==i issues one atomic per row-strip. khalf 0/1 hold
    // DIFFERENT rows (row = (i&3)+8*(i>>2)+4*khalf) — no double-writes.
#pragma unroll
    for (int i = 0; i < 16; ++i) {
        float v[RPW];
#pragma unroll
        for (int r = 0; r < RPW; ++r) v[r] = acc[r][i];
#pragma unroll
        for (int off = 1; off < 32; off <<= 1) {
#pragma unroll
            for (int r = 0; r < RPW; ++r)
                v[r] = fminf(v[r], __shfl_xor(v[r], off, 64));
        }
        if (l31 == i) {
            const int row = (i & 3) + 8 * (i >> 2) + 4 * khalf;
#pragma unroll
            for (int r = 0; r < RPW; ++r)
                atomicMin(outbase + r0 + r * 32 + row, __float_as_int(v[r]));
        }
    }
}

// Safety fallback if ws is too small.
__global__ __launch_bounds__(BLK) void chamfer_fallback(
    const float* __restrict__ xyz1, const float* __restrict__ xyz2,
    float* __restrict__ out, int B, int N, int M)
{
    const int dir = blockIdx.z;
    const int b   = blockIdx.y;
    const float* Q = (dir == 0) ? xyz1 : xyz2;
    const float* T = (dir == 0) ? xyz2 : xyz1;
    const int nQ = (dir == 0) ? N : M;
    const int nT = (dir == 0) ? M : N;
    const int i = blockIdx.x * BLK + threadIdx.x;

    float x0 = 0.f, x1 = 0.f, x2 = 0.f;
    if (i < nQ) {
        const float* q = Q + ((size_t)b * nQ + i) * 3;
        x0 = q[0]; x1 = q[1]; x2 = q[2];
    }
    float best = FLT_MAX;
    for (int jj = 0; jj < nT; ++jj) {
        const float* t = T + ((size_t)b * nT + jj) * 3;
        float t0 = t[0] - x0, t1 = t[1] - x1, t2 = t[2] - x2;
        best = fminf(best, fmaf(t0, t0, fmaf(t1, t1, t2 * t2)));
    }
    if (i < nQ) {
        const size_t off = (dir == 0) ? ((size_t)b * N + i)
                                      : ((size_t)B * N + (size_t)b * M + i);
        out[off] = best;
    }
}

extern "C" void kernel_launch(void* const* d_in, const int* in_sizes, int n_in,
                              void* d_out, int out_size, void* d_ws, size_t ws_size,
                              hipStream_t stream) {
    const float* xyz1 = (const float*)d_in[0];
    const float* xyz2 = (const float*)d_in[1];

    const int npts = NB * NPTS;                   // 65536 points per set
    const size_t buf = (size_t)npts * 32;         // 2 MB per layout buffer

    if (ws_size >= 4 * buf) {
        unsigned short* Aq1 = (unsigned short*)d_ws;
        unsigned short* Bt1 = (unsigned short*)((char*)d_ws + buf);
        unsigned short* Aq2 = (unsigned short*)((char*)d_ws + 2*buf);
        unsigned short* Bt2 = (unsigned short*)((char*)d_ws + 3*buf);
        int* outI = (int*)d_out;

        prep_kernel<<<(npts + BLK - 1) / BLK, BLK, 0, stream>>>(
            xyz1, xyz2, Aq1, Bt1, Aq2, Bt2, outI, npts);

        // x = strip*16 + zrole: zrole -> 2 (dir,chunk) roles per XCD.
        dim3 grid(16 * (NPTS / 32 / (WPB * RPW)), NB, 1);   // (512, 8, 1) = 4096 blocks
        chamfer_mfma<<<grid, dim3(BLK, 1, 1), 0, stream>>>(
            (const bf16x8*)Aq1, (const bf16x8*)Bt1,
            (const bf16x8*)Aq2, (const bf16x8*)Bt2, outI);
    } else {
        dim3 grid((NPTS + BLK - 1) / BLK, NB, 2);
        chamfer_fallback<<<grid, dim3(BLK, 1, 1), 0, stream>>>(
            xyz1, xyz2, (float*)d_out, NB, NPTS, NPTS);
    }
}

// Round 27
// 55.855 us; speedup vs baseline: 1.1597x; 1.1597x over previous
//
#include <hip/hip_runtime.h>
#include <float.h>

#define BLK 256
#define NB 8
#define NPTS 8192
#define WPB 4      // waves per block
#define RPW 2      // 32-row strips (A fragments) per wave
#define CSPLIT 4   // column chunks per (batch, dir) — 1 role/XCD (r23/r25 proven)
#define GPTS 64    // points per group (2 tiles)
#define NG (NPTS / CSPLIT / GPTS)   // 32 groups per chunk

typedef short bf16x8 __attribute__((ext_vector_type(8)));
typedef float f32x16 __attribute__((ext_vector_type(16)));

static __device__ __forceinline__ unsigned short f2bf(float f) {   // RNE f32->bf16
    union { float f; unsigned int u; } v; v.f = f;
    unsigned int u = v.u + 0x7FFFu + ((v.u >> 16) & 1u);
    return (unsigned short)(u >> 16);
}
static __device__ __forceinline__ float bf2f(unsigned short h) {
    union { unsigned int u; float f; } v; v.u = ((unsigned int)h) << 16;
    return v.f;
}

// Prep + fused output-init (saves the separate init_out launch — the only
// r26 change kept; CSPLIT=8 reverted since it broke L2 residency,
// FETCH 10.3->18.5 MB).
// Emits BOTH layouts for BOTH point sets (K=16 bf16 slots; r13/r17-verified):
//   query layout:  [qh0..2, ql0..2, qh0..2, ql0..2, 1, 1, x2h, x2l]
//   target layout: [th0..2, th0..2, tl0..2, tl0..2, wh, wl, 1, 1], t=-2y, w=||y||^2
// Sum_k A_k*B_k = ||x||^2 + ||y||^2 - 2 x.y  (bf16 products exact in f32).
__global__ __launch_bounds__(BLK) void prep_kernel(
    const float* __restrict__ xyz1, const float* __restrict__ xyz2,
    unsigned short* __restrict__ Aq1, unsigned short* __restrict__ Bt1,
    unsigned short* __restrict__ Aq2, unsigned short* __restrict__ Bt2,
    int* __restrict__ outI, int npts)
{
    const int i = blockIdx.x * BLK + threadIdx.x;
    if (i >= npts) return;
    outI[i]        = 0x7F800000;   // +inf bits; atomicMin-as-int = float min (r10-r25 proven)
    outI[i + npts] = 0x7F800000;
    const unsigned short one = 0x3F80;
    const float* srcs[2] = { xyz1, xyz2 };
    unsigned short* aouts[2] = { Aq1, Aq2 };
    unsigned short* bouts[2] = { Bt1, Bt2 };
#pragma unroll
    for (int s = 0; s < 2; ++s) {
        const float p0 = srcs[s][3*(size_t)i], p1 = srcs[s][3*(size_t)i+1], p2 = srcs[s][3*(size_t)i+2];
        {
            const unsigned short h0 = f2bf(p0), h1 = f2bf(p1), h2 = f2bf(p2);
            const unsigned short l0 = f2bf(p0 - bf2f(h0)), l1 = f2bf(p1 - bf2f(h1)), l2 = f2bf(p2 - bf2f(h2));
            const float q2 = fmaf(p0, p0, fmaf(p1, p1, p2 * p2));
            const unsigned short q2h = f2bf(q2), q2l = f2bf(q2 - bf2f(q2h));
            unsigned short* o = aouts[s] + 16*(size_t)i;
            o[0]=h0; o[1]=h1; o[2]=h2; o[3]=l0; o[4]=l1; o[5]=l2;
            o[6]=h0; o[7]=h1; o[8]=h2; o[9]=l0; o[10]=l1; o[11]=l2;
            o[12]=one; o[13]=one; o[14]=q2h; o[15]=q2l;
        }
        {
            const float t0 = -2.f*p0, t1 = -2.f*p1, t2 = -2.f*p2;
            const unsigned short h0 = f2bf(t0), h1 = f2bf(t1), h2 = f2bf(t2);
            const unsigned short l0 = f2bf(t0 - bf2f(h0)), l1 = f2bf(t1 - bf2f(h1)), l2 = f2bf(t2 - bf2f(h2));
            const float w = fmaf(p0, p0, fmaf(p1, p1, p2 * p2));
            const unsigned short wh = f2bf(w), wl = f2bf(w - bf2f(wh));
            unsigned short* o = bouts[s] + 16*(size_t)i;
            o[0]=h0; o[1]=h1; o[2]=h2; o[3]=h0; o[4]=h1; o[5]=h2;
            o[6]=l0; o[7]=l1; o[8]=l2; o[9]=l0; o[10]=l1; o[11]=l2;
            o[12]=wh; o[13]=wl; o[14]=one; o[15]=one;
        }
    }
}

struct G2 { bf16x8 v0, v1; };

// Row-min MFMA passes — r25 balanced core (session best: 48.9 us main):
// RPW=2, XCD role map (blockIdx.x&7 -> ONE (dir,chunk) per XCD; FETCH -45%),
// 2-tile groups + 1-ahead prefetch + 2 live d-tiles, launch_bounds(BLK,4).
__global__ __launch_bounds__(BLK, 4) void chamfer_mfma(
    const bf16x8* __restrict__ Aq1, const bf16x8* __restrict__ Bt1,
    const bf16x8* __restrict__ Aq2, const bf16x8* __restrict__ Bt2,
    int* __restrict__ outI)
{
    const int wave  = threadIdx.x >> 6;
    const int lane  = threadIdx.x & 63;
    const int l31   = lane & 31;
    const int khalf = lane >> 5;

    const int zrole = blockIdx.x & 7;      // -> XCD-aligned (dispatch % 8)
    const int strip = blockIdx.x >> 3;     // [0, 32)
    const int dir   = zrole >> 2;
    const int chunk = zrole & 3;
    const int batch = blockIdx.y;

    const bf16x8* __restrict__ A  = dir ? Aq2 : Aq1;
    const bf16x8* __restrict__ Bt = dir ? Bt1 : Bt2;
    int* outbase = outI + (size_t)dir * NB * NPTS + (size_t)batch * NPTS;

    const size_t pbase = (size_t)batch * NPTS;
    const int r0 = (strip * WPB + wave) * (RPW * 32);

    bf16x8 afrag[RPW];
#pragma unroll
    for (int r = 0; r < RPW; ++r)
        afrag[r] = A[(pbase + r0 + r * 32 + l31) * 2 + khalf];

    float acc[RPW][16];
#pragma unroll
    for (int r = 0; r < RPW; ++r)
#pragma unroll
        for (int i = 0; i < 16; ++i) acc[r][i] = FLT_MAX;

    const size_t cbase = pbase + (size_t)chunk * (NPTS / CSPLIT);   // chunk point base

    auto LOADG = [&](int g) -> G2 {
        const size_t m = cbase + (size_t)g * GPTS + l31;
        G2 p;
        p.v0 = Bt[(m     ) * 2 + khalf];
        p.v1 = Bt[(m + 32) * 2 + khalf];
        return p;
    };

    const f32x16 zero = {};
    auto CONSUME = [&](const G2& p) {
#pragma unroll
        for (int r = 0; r < RPW; ++r) {    // 2 d-tiles live at a time
            const f32x16 dA = __builtin_amdgcn_mfma_f32_32x32x16_bf16(afrag[r], p.v0, zero, 0, 0, 0);
            const f32x16 dB = __builtin_amdgcn_mfma_f32_32x32x16_bf16(afrag[r], p.v1, zero, 0, 0, 0);
#pragma unroll
            for (int i = 0; i < 16; ++i)   // one fused v_min3 folds both tiles
                acc[r][i] = fminf(fminf(dA[i], dB[i]), acc[r][i]);
        }
    };

    // 1-group-ahead pipeline (static names — rule #20).
    G2 cur = LOADG(0);
    for (int g = 0; g < NG; ++g) {
        G2 nxt = (g + 1 < NG) ? LOADG(g + 1) : cur;
        CONSUME(cur);
        cur = nxt;
    }

    // Epilogue: butterfly min over the 32 lanes (cols) of each khalf group,
    // then lane l31==i issues one atomic per row-strip. khalf 0/1 hold
    // DIFFERENT rows (row = (i&3)+8*(i>>2)+4*khalf) — no double-writes.
#pragma unroll
    for (int i = 0; i < 16; ++i) {
        float v[RPW];
#pragma unroll
        for (int r = 0; r < RPW; ++r) v[r] = acc[r][i];
#pragma unroll
        for (int off = 1; off < 32; off <<= 1) {
#pragma unroll
            for (int r = 0; r < RPW; ++r)
                v[r] = fminf(v[r], __shfl_xor(v[r], off, 64));
        }
        if (l31 == i) {
            const int row = (i & 3) + 8 * (i >> 2) + 4 * khalf;
#pragma unroll
            for (int r = 0; r < RPW; ++r)
                atomicMin(outbase + r0 + r * 32 + row, __float_as_int(v[r]));
        }
    }
}

// Safety fallback if ws is too small.
__global__ __launch_bounds__(BLK) void chamfer_fallback(
    const float* __restrict__ xyz1, const float* __restrict__ xyz2,
    float* __restrict__ out, int B, int N, int M)
{
    const int dir = blockIdx.z;
    const int b   = blockIdx.y;
    const float* Q = (dir == 0) ? xyz1 : xyz2;
    const float* T = (dir == 0) ? xyz2 : xyz1;
    const int nQ = (dir == 0) ? N : M;
    const int nT = (dir == 0) ? M : N;
    const int i = blockIdx.x * BLK + threadIdx.x;

    float x0 = 0.f, x1 = 0.f, x2 = 0.f;
    if (i < nQ) {
        const float* q = Q + ((size_t)b * nQ + i) * 3;
        x0 = q[0]; x1 = q[1]; x2 = q[2];
    }
    float best = FLT_MAX;
    for (int jj = 0; jj < nT; ++jj) {
        const float* t = T + ((size_t)b * nT + jj) * 3;
        float t0 = t[0] - x0, t1 = t[1] - x1, t2 = t[2] - x2;
        best = fminf(best, fmaf(t0, t0, fmaf(t1, t1, t2 * t2)));
    }
    if (i < nQ) {
        const size_t off = (dir == 0) ? ((size_t)b * N + i)
                                      : ((size_t)B * N + (size_t)b * M + i);
        out[off] = best;
    }
}

extern "C" void kernel_launch(void* const* d_in, const int* in_sizes, int n_in,
                              void* d_out, int out_size, void* d_ws, size_t ws_size,
                              hipStream_t stream) {
    const float* xyz1 = (const float*)d_in[0];
    const float* xyz2 = (const float*)d_in[1];

    const int npts = NB * NPTS;                   // 65536 points per set
    const size_t buf = (size_t)npts * 32;         // 2 MB per layout buffer

    if (ws_size >= 4 * buf) {
        unsigned short* Aq1 = (unsigned short*)d_ws;
        unsigned short* Bt1 = (unsigned short*)((char*)d_ws + buf);
        unsigned short* Aq2 = (unsigned short*)((char*)d_ws + 2*buf);
        unsigned short* Bt2 = (unsigned short*)((char*)d_ws + 3*buf);
        int* outI = (int*)d_out;

        prep_kernel<<<(npts + BLK - 1) / BLK, BLK, 0, stream>>>(
            xyz1, xyz2, Aq1, Bt1, Aq2, Bt2, outI, npts);

        // x = strip*8 + zrole: zrole==linear%8 -> one (dir,chunk) per XCD.
        dim3 grid(8 * (NPTS / 32 / (WPB * RPW)), NB, 1);   // (256, 8, 1) = 2048 blocks
        chamfer_mfma<<<grid, dim3(BLK, 1, 1), 0, stream>>>(
            (const bf16x8*)Aq1, (const bf16x8*)Bt1,
            (const bf16x8*)Aq2, (const bf16x8*)Bt2, outI);
    } else {
        dim3 grid((NPTS + BLK - 1) / BLK, NB, 2);
        chamfer_fallback<<<grid, dim3(BLK, 1, 1), 0, stream>>>(
            xyz1, xyz2, (float*)d_out, NB, NPTS, NPTS);
    }
}